// Round 1
// baseline (1301.029 us; speedup 1.0000x reference)
//
#include <hip/hip_runtime.h>
#include <math.h>

#define LQ 1024
#define HH 8
#define BB 4
#define EE 64
#define NP (BB * HH)
#define NJ 25
#define SCALE 0.125f

// P[pair, l, j] = scale * dot(x[b,l,h,:], rel_k_table[j,:])
__global__ __launch_bounds__(64) void k_relproj(const float* __restrict__ x,
                                                const float* __restrict__ relk,
                                                float* __restrict__ P) {
  int blk = blockIdx.x;
  int pair = blk >> 10;
  int l = blk & (LQ - 1);
  int b = pair >> 3, h = pair & 7;
  __shared__ float xs[EE];
  int tid = threadIdx.x;
  xs[tid] = x[((size_t)(b * LQ + l) * HH + h) * EE + tid];
  __syncthreads();
  if (tid < NJ) {
    float acc = 0.f;
#pragma unroll
    for (int e = 0; e < EE; ++e) acc += xs[e] * relk[tid * EE + e];
    P[((size_t)pair * LQ + l) * NJ + tid] = SCALE * acc;
  }
}

// S[l,s] = scale * dot(x[l], y[s]) + P[l, clip(s-l)+12]
__global__ __launch_bounds__(256) void k_scores(const float* __restrict__ x,
                                                const float* __restrict__ y,
                                                const float* __restrict__ P,
                                                float* __restrict__ S, int g0) {
  int pair = g0 + blockIdx.z;
  int b = pair >> 3, h = pair & 7;
  int s0 = blockIdx.x * 64, l0 = blockIdx.y * 64;
  __shared__ float Xs[64][65];
  __shared__ float Ys[64][65];
  int tid = threadIdx.x;
  for (int idx = tid; idx < 64 * 64; idx += 256) {
    int r = idx >> 6, e = idx & 63;
    Xs[r][e] = x[((size_t)(b * LQ + l0 + r) * HH + h) * EE + e];
    Ys[r][e] = y[((size_t)(b * LQ + s0 + r) * HH + h) * EE + e];
  }
  __syncthreads();
  int tx = tid & 15, ty = tid >> 4;
  float acc[4][4] = {};
  for (int e = 0; e < 64; ++e) {
    float a[4], bb[4];
#pragma unroll
    for (int i = 0; i < 4; ++i) a[i] = Xs[ty * 4 + i][e];
#pragma unroll
    for (int j = 0; j < 4; ++j) bb[j] = Ys[tx * 4 + j][e];
#pragma unroll
    for (int i = 0; i < 4; ++i)
#pragma unroll
      for (int j = 0; j < 4; ++j) acc[i][j] += a[i] * bb[j];
  }
  float* Sp = S + (size_t)blockIdx.z * LQ * LQ;
#pragma unroll
  for (int i = 0; i < 4; ++i) {
    int l = l0 + ty * 4 + i;
    const float* Prow = P + ((size_t)pair * LQ + l) * NJ;
#pragma unroll
    for (int j = 0; j < 4; ++j) {
      int s = s0 + tx * 4 + j;
      int dlt = s - l;
      dlt = dlt < -12 ? -12 : (dlt > 12 ? 12 : dlt);
      Sp[(size_t)l * LQ + s] = SCALE * acc[i][j] + Prow[dlt + 12];
    }
  }
}

// row max / sumexp
__global__ __launch_bounds__(256) void k_rowstats(const float* __restrict__ S,
                                                  float* __restrict__ m1,
                                                  float* __restrict__ s1, int g0) {
  int pair = g0 + blockIdx.y;
  int l = blockIdx.x;
  const float* row = S + (size_t)blockIdx.y * LQ * LQ + (size_t)l * LQ;
  int tid = threadIdx.x;
  __shared__ float red[8];
  float m = -3.0e38f;
  for (int s = tid; s < LQ; s += 256) m = fmaxf(m, row[s]);
  for (int o = 32; o > 0; o >>= 1) m = fmaxf(m, __shfl_xor(m, o));
  int w = tid >> 6;
  if ((tid & 63) == 0) red[w] = m;
  __syncthreads();
  m = fmaxf(fmaxf(red[0], red[1]), fmaxf(red[2], red[3]));
  float sum = 0.f;
  for (int s = tid; s < LQ; s += 256) sum += __expf(row[s] - m);
  for (int o = 32; o > 0; o >>= 1) sum += __shfl_xor(sum, o);
  if ((tid & 63) == 0) red[4 + w] = sum;
  __syncthreads();
  if (tid == 0) {
    m1[(size_t)pair * LQ + l] = m;
    s1[(size_t)pair * LQ + l] = red[4] + red[5] + red[6] + red[7];
  }
}

// column max / sumexp (online over rows; threads own consecutive columns)
__global__ __launch_bounds__(256) void k_colstats(const float* __restrict__ S,
                                                  float* __restrict__ mc,
                                                  float* __restrict__ sc, int g0) {
  int pair = g0 + blockIdx.y;
  int col = blockIdx.x * 256 + threadIdx.x;
  const float* Sp = S + (size_t)blockIdx.y * LQ * LQ;
  float m = -3.0e38f, sum = 0.f;
  for (int l = 0; l < LQ; ++l) {
    float v = Sp[(size_t)l * LQ + col];
    float nm = fmaxf(m, v);
    sum = sum * __expf(m - nm) + __expf(v - nm);
    m = nm;
  }
  mc[(size_t)pair * LQ + col] = m;
  sc[(size_t)pair * LQ + col] = sum;
}

// out[b, l, h, d] = sum_s A[l,s] * (v[b,s,h,d] + tab[clip(s-l)+12, d])
// TR=0: A from rows of S with (m1,s1);  TR=1: A from columns of S with (mc,sc)
template <int TR>
__global__ __launch_bounds__(256) void k_av(const float* __restrict__ S,
                                            const float* __restrict__ v,
                                            const float* __restrict__ tabg,
                                            const float* __restrict__ mArr,
                                            const float* __restrict__ sArr,
                                            float* __restrict__ out, int g0) {
  int pair = g0 + blockIdx.y;
  int b = pair >> 3, h = pair & 7;
  int l0 = blockIdx.x * 8;
  int tid = threadIdx.x;
  __shared__ float tab[NJ * EE];
  __shared__ float ms[8], is[8];
  __shared__ float redu[4][8][64];
  for (int idx = tid; idx < NJ * EE; idx += 256) tab[idx] = tabg[idx];
  if (tid < 8) {
    ms[tid] = mArr[(size_t)pair * LQ + l0 + tid];
    is[tid] = 1.f / sArr[(size_t)pair * LQ + l0 + tid];
  }
  __syncthreads();
  int d = tid & 63, w = tid >> 6;
  const float* Sp = S + (size_t)blockIdx.y * LQ * LQ;
  float acc[8] = {};
  for (int s = w; s < LQ; s += 4) {
    float vv = v[((size_t)(b * LQ + s) * HH + h) * EE + d];
#pragma unroll
    for (int r = 0; r < 8; ++r) {
      float sv = TR ? Sp[(size_t)s * LQ + (l0 + r)] : Sp[(size_t)(l0 + r) * LQ + s];
      float a = __expf(sv - ms[r]) * is[r];
      int dlt = s - (l0 + r);
      dlt = dlt < -12 ? -12 : (dlt > 12 ? 12 : dlt);
      acc[r] += a * (vv + tab[(dlt + 12) * EE + d]);
    }
  }
#pragma unroll
  for (int r = 0; r < 8; ++r) redu[w][r][d] = acc[r];
  __syncthreads();
  if (w == 0) {
#pragma unroll
    for (int r = 0; r < 8; ++r) {
      float val = redu[0][r][d] + redu[1][r][d] + redu[2][r][d] + redu[3][r][d];
      out[((size_t)(b * LQ + l0 + r) * HH + h) * EE + d] = val;
    }
  }
}

extern "C" void kernel_launch(void* const* d_in, const int* in_sizes, int n_in,
                              void* d_out, int out_size, void* d_ws, size_t ws_size,
                              hipStream_t stream) {
  const float* x = (const float*)d_in[0];
  const float* y = (const float*)d_in[1];
  const float* vx = (const float*)d_in[2];
  const float* vy = (const float*)d_in[3];
  const float* relk = (const float*)d_in[4];
  const float* relvx = (const float*)d_in[5];
  const float* relvy = (const float*)d_in[6];
  float* out = (float*)d_out;
  float* out2 = out + (size_t)BB * LQ * HH * EE;

  // workspace layout: [P | m1 | s1 | mc | sc | S(chunked)]
  float* P = (float*)d_ws;
  size_t pfl = (size_t)NP * LQ * NJ;
  float* m1 = P + pfl;
  float* s1 = m1 + (size_t)NP * LQ;
  float* mc = s1 + (size_t)NP * LQ;
  float* sc = mc + (size_t)NP * LQ;
  size_t tail_bytes = (pfl + 4ull * NP * LQ) * sizeof(float);
  size_t s_off = (tail_bytes + 255) & ~(size_t)255;
  float* S = (float*)((char*)d_ws + s_off);
  size_t scap = ws_size > s_off ? (ws_size - s_off) : 0;
  int cap = (int)(scap / ((size_t)LQ * LQ * sizeof(float)));
  if (cap < 1) cap = 1;
  if (cap > NP) cap = NP;

  k_relproj<<<NP * LQ, 64, 0, stream>>>(x, relk, P);
  for (int g0 = 0; g0 < NP; g0 += cap) {
    int gp = (NP - g0) < cap ? (NP - g0) : cap;
    k_scores<<<dim3(16, 16, gp), 256, 0, stream>>>(x, y, P, S, g0);
    k_rowstats<<<dim3(LQ, gp), 256, 0, stream>>>(S, m1, s1, g0);
    k_colstats<<<dim3(LQ / 256, gp), 256, 0, stream>>>(S, mc, sc, g0);
    k_av<0><<<dim3(LQ / 8, gp), 256, 0, stream>>>(S, vy, relvy, m1, s1, out, g0);
    k_av<1><<<dim3(LQ / 8, gp), 256, 0, stream>>>(S, vx, relvx, mc, sc, out2, g0);
  }
}

// Round 3
// 150.999 us; speedup vs baseline: 8.6161x; 8.6161x over previous
//
#include <hip/hip_runtime.h>
#include <math.h>

#define LQ 1024
#define HH 8
#define BB 4
#define EE 64
#define NP (BB * HH)
#define ROWSTRIDE 512   // H*E floats between consecutive l in [B,L,H,E]
#define PJ 26           // padded j-stride for P
#define SCALE 0.125f

typedef __attribute__((ext_vector_type(4))) float f32x4;
typedef __attribute__((ext_vector_type(8))) short short8x;
typedef __attribute__((ext_vector_type(4))) short short4x;

__device__ __forceinline__ unsigned short f2bf(float f) {
  unsigned u = __float_as_uint(f);
  u += 0x7fffu + ((u >> 16) & 1u);
  return (unsigned short)(u >> 16);
}

// swizzled LDS byte address for a [rows][64 bf16] tile (row stride 128B)
__device__ __forceinline__ int swz(int row, int bytecol) {
  return row * 128 + (bytecol ^ ((row & 7) << 4));
}

// P[pair, l, j] = scale * dot(x[b,l,h,:], rel_k_table[j,:])   (j = 0..24)
__global__ __launch_bounds__(64) void k_relproj(const float* __restrict__ x,
                                                const float* __restrict__ relk,
                                                float* __restrict__ P) {
  int blk = blockIdx.x;
  int pair = blk >> 10;
  int l = blk & (LQ - 1);
  int b = pair >> 3, h = pair & 7;
  __shared__ float xs[EE];
  int tid = threadIdx.x;
  xs[tid] = x[(size_t)b * 524288 + (size_t)l * ROWSTRIDE + h * 64 + tid];
  __syncthreads();
  if (tid < 25) {
    float acc = 0.f;
#pragma unroll
    for (int e = 0; e < EE; ++e) acc += xs[e] * relk[tid * EE + e];
    P[((size_t)pair * LQ + l) * PJ + tid] = SCALE * acc;
  }
}

// stage a 64x64 f32 tile (row stride ROWSTRIDE) -> bf16 swizzled LDS, optional scale
__device__ __forceinline__ void stage_tile(char* dst, const float* src, int tid, float sc) {
  const int row = tid >> 2, q = tid & 3;
  const float* s = src + (size_t)row * ROWSTRIDE + q * 16;
#pragma unroll
  for (int hh = 0; hh < 2; ++hh) {
    float4 a = *(const float4*)(s + hh * 8);
    float4 b = *(const float4*)(s + hh * 8 + 4);
    short8x v;
    v[0] = (short)f2bf(a.x * sc); v[1] = (short)f2bf(a.y * sc);
    v[2] = (short)f2bf(a.z * sc); v[3] = (short)f2bf(a.w * sc);
    v[4] = (short)f2bf(b.x * sc); v[5] = (short)f2bf(b.y * sc);
    v[6] = (short)f2bf(b.z * sc); v[7] = (short)f2bf(b.w * sc);
    *(short8x*)(dst + swz(row, q * 32 + hh * 16)) = v;
  }
}

// stage a 64x64 f32 V tile TRANSPOSED -> VT[d][s] bf16 swizzled LDS
__device__ __forceinline__ void stage_vt(char* dst, const float* src, int tid) {
  const int sb = tid >> 4, db = tid & 15;
  const float* s = src + (size_t)sb * 4 * ROWSTRIDE + db * 4;
  float4 r0 = *(const float4*)(s);
  float4 r1 = *(const float4*)(s + ROWSTRIDE);
  float4 r2 = *(const float4*)(s + 2 * ROWSTRIDE);
  float4 r3 = *(const float4*)(s + 3 * ROWSTRIDE);
  short4x v;
  v[0] = (short)f2bf(r0.x); v[1] = (short)f2bf(r1.x); v[2] = (short)f2bf(r2.x); v[3] = (short)f2bf(r3.x);
  *(short4x*)(dst + swz(db * 4 + 0, sb * 8)) = v;
  v[0] = (short)f2bf(r0.y); v[1] = (short)f2bf(r1.y); v[2] = (short)f2bf(r2.y); v[3] = (short)f2bf(r3.y);
  *(short4x*)(dst + swz(db * 4 + 1, sb * 8)) = v;
  v[0] = (short)f2bf(r0.z); v[1] = (short)f2bf(r1.z); v[2] = (short)f2bf(r2.z); v[3] = (short)f2bf(r3.z);
  *(short4x*)(dst + swz(db * 4 + 2, sb * 8)) = v;
  v[0] = (short)f2bf(r0.w); v[1] = (short)f2bf(r1.w); v[2] = (short)f2bf(r2.w); v[3] = (short)f2bf(r3.w);
  *(short4x*)(dst + swz(db * 4 + 3, sb * 8)) = v;
}

// stage 64 rows x 25 j of P into [64][PJ] f32 LDS
__device__ __forceinline__ void stage_p(float* dstP, const float* Pg, int tid) {
  const int row = tid >> 2, q = tid & 3;
#pragma unroll
  for (int j = q; j < 25; j += 4) dstP[row * PJ + j] = Pg[(size_t)row * PJ + j];
}

// MODE 0: V_Y path (Afix = x*scale, Bloop = y, bias = P[l][j], V = v_y, tab = rel_vy)
// MODE 1: V_X path (Afix = y*scale, Bloop = x, bias = P[s][24-j], V = v_x, tab = rel_vx)
// j = clip(s - l, -12, 12) + 12
template <int MODE>
__global__ __launch_bounds__(256, 2) void k_fused(const float* __restrict__ Afix_g,
                                                  const float* __restrict__ Bloop_g,
                                                  const float* __restrict__ V_g,
                                                  const float* __restrict__ tab_g,
                                                  const float* __restrict__ P_g,
                                                  float* __restrict__ out_g) {
  __shared__ __align__(16) char ldsA[8192];
  __shared__ __align__(16) char ldsB[2][8192];
  __shared__ __align__(16) char ldsVT[2][8192];
  __shared__ float ldsP[2][64 * PJ];
  __shared__ __align__(16) char ldsEA[4][2048];
  __shared__ float ldsW[64 * PJ];
  __shared__ float ldsTab[25 * 64];

  const int tid = threadIdx.x;
  const int pair = blockIdx.y;
  const int b = pair >> 3, h = pair & 7;
  const int l0 = blockIdx.x * 64;

  const float* abase = Afix_g + (size_t)b * 524288 + h * 64;
  const float* bbase = Bloop_g + (size_t)b * 524288 + h * 64;
  const float* vbase = V_g + (size_t)b * 524288 + h * 64;
  const float* Pbase = P_g + (size_t)pair * LQ * PJ;
  float* outb = out_g + (size_t)b * 524288 + h * 64;

  // ---- prologue staging ----
  stage_tile(ldsA, abase + (size_t)l0 * ROWSTRIDE, tid, SCALE);
  if (MODE == 0) stage_p(ldsP[0], Pbase + (size_t)l0 * PJ, tid);
  else stage_p(ldsP[0], Pbase, tid);  // s-range of step 0
  stage_tile(ldsB[0], bbase, tid, 1.0f);
  stage_vt(ldsVT[0], vbase, tid);
  for (int idx = tid; idx < 25 * 64; idx += 256) ldsTab[idx] = tab_g[idx];
  for (int idx = tid; idx < 64 * PJ; idx += 256) ldsW[idx] = 0.f;
  __syncthreads();

  const int lane = tid & 63, wv = tid >> 6;
  const int col16 = lane & 15, rg = lane >> 4;

  // hoisted A fragments (rows = wave strip, fixed all steps)
  short8x af0 = *(const short8x*)(ldsA + swz(wv * 16 + col16, rg * 16));
  short8x af1 = *(const short8x*)(ldsA + swz(wv * 16 + col16, 64 + rg * 16));

  float bL[4], bR[4];
  if (MODE == 0) {
#pragma unroll
    for (int r = 0; r < 4; ++r) {
      int row = wv * 16 + rg * 4 + r;
      bL[r] = ldsP[0][row * PJ + 0];
      bR[r] = ldsP[0][row * PJ + 24];
    }
  }

  f32x4 accO[4];
  float rowsum[4], wl[4], wr[4];
#pragma unroll
  for (int r = 0; r < 4; ++r) { rowsum[r] = 0.f; wl[r] = 0.f; wr[r] = 0.f; }
  const f32x4 z4 = {0.f, 0.f, 0.f, 0.f};
#pragma unroll
  for (int dt = 0; dt < 4; ++dt) accO[dt] = z4;

  char* ea = ldsEA[wv];

  for (int t = 0; t < 16; ++t) {
    if (t < 15) {
      int nb = (t + 1) & 1;
      stage_tile(ldsB[nb], bbase + (size_t)(t + 1) * 64 * ROWSTRIDE, tid, 1.0f);
      stage_vt(ldsVT[nb], vbase + (size_t)(t + 1) * 64 * ROWSTRIDE, tid);
      if (MODE == 1) stage_p(ldsP[nb], Pbase + (size_t)(t + 1) * 64 * PJ, tid);
    }
    const int cb = t & 1;
    const char* bB = ldsB[cb];
    const char* vB = ldsVT[cb];

    // ---- T = Afix · Bloop^T (16x64 strip per wave) ----
    f32x4 accS[4];
#pragma unroll
    for (int ct = 0; ct < 4; ++ct) {
      short8x bf0 = *(const short8x*)(bB + swz(ct * 16 + col16, rg * 16));
      short8x bf1 = *(const short8x*)(bB + swz(ct * 16 + col16, 64 + rg * 16));
      f32x4 tacc = __builtin_amdgcn_mfma_f32_16x16x32_bf16(af0, bf0, z4, 0, 0, 0);
      accS[ct] = __builtin_amdgcn_mfma_f32_16x16x32_bf16(af1, bf1, tacc, 0, 0, 0);
    }

    // ---- epilogue: bias, exp, rowsum, rel-V buckets, E -> bf16 LDS ----
    const int rel0 = t * 64 - l0;
    if (rel0 < -74 || rel0 > 74) {  // fast path: whole tile is one tail side
      const bool right = rel0 > 0;
      float bias_c[4];
      if (MODE == 1) {
#pragma unroll
        for (int ct = 0; ct < 4; ++ct)
          bias_c[ct] = ldsP[cb][(ct * 16 + col16) * PJ + (right ? 0 : 24)];
      }
#pragma unroll
      for (int ct = 0; ct < 4; ++ct) {
#pragma unroll
        for (int r = 0; r < 4; ++r) {
          float bias = (MODE == 0) ? (right ? bR[r] : bL[r]) : bias_c[ct];
          float e = __expf(accS[ct][r] + bias);
          rowsum[r] += e;
          if (right) wr[r] += e; else wl[r] += e;
          *(short*)(ea + swz(rg * 4 + r, (ct * 16 + col16) * 2)) = (short)f2bf(e);
        }
      }
    } else {  // band path: per-element clip/gather
#pragma unroll
      for (int ct = 0; ct < 4; ++ct) {
#pragma unroll
        for (int r = 0; r < 4; ++r) {
          const int row = wv * 16 + rg * 4 + r;
          const int d = rel0 + ct * 16 + col16 - row;
          int j = d < -12 ? -12 : (d > 12 ? 12 : d);
          j += 12;
          float bias = (MODE == 0) ? ldsP[0][row * PJ + j]
                                   : ldsP[cb][(ct * 16 + col16) * PJ + (24 - j)];
          float e = __expf(accS[ct][r] + bias);
          rowsum[r] += e;
          if (d <= -12) wl[r] += e;
          else if (d >= 12) wr[r] += e;
          else ldsW[row * PJ + j] = e;  // unique (row,j), j in [1,23]
          *(short*)(ea + swz(rg * 4 + r, (ct * 16 + col16) * 2)) = (short)f2bf(e);
        }
      }
    }

    // make E-writes visible to the vector reads below (compiler fence + HW barrier)
    asm volatile("" ::: "memory");
    __syncthreads();

    // ---- AV: O += E · V  (E repacked via per-wave LDS) ----
    short8x ef0 = *(const short8x*)(ea + swz(col16, rg * 16));
    short8x ef1 = *(const short8x*)(ea + swz(col16, 64 + rg * 16));
#pragma unroll
    for (int dt = 0; dt < 4; ++dt) {
      short8x v0 = *(const short8x*)(vB + swz(dt * 16 + col16, rg * 16));
      short8x v1 = *(const short8x*)(vB + swz(dt * 16 + col16, 64 + rg * 16));
      f32x4 tacc = __builtin_amdgcn_mfma_f32_16x16x32_bf16(ef0, v0, accO[dt], 0, 0, 0);
      accO[dt] = __builtin_amdgcn_mfma_f32_16x16x32_bf16(ef1, v1, tacc, 0, 0, 0);
    }
    __syncthreads();
  }

  // ---- final: reduce row stats across the 16 col-lanes, rel-V, normalize, store ----
#pragma unroll
  for (int r = 0; r < 4; ++r) {
#pragma unroll
    for (int m = 1; m < 16; m <<= 1) {
      rowsum[r] += __shfl_xor(rowsum[r], m);
      wl[r] += __shfl_xor(wl[r], m);
      wr[r] += __shfl_xor(wr[r], m);
    }
  }
  float inv[4];
#pragma unroll
  for (int r = 0; r < 4; ++r) inv[r] = 1.f / rowsum[r];

#pragma unroll
  for (int dt = 0; dt < 4; ++dt) {
#pragma unroll
    for (int r = 0; r < 4; ++r) {
      int row = wv * 16 + rg * 4 + r;
      int dd = dt * 16 + col16;
      float vr = wl[r] * ldsTab[0 * 64 + dd] + wr[r] * ldsTab[24 * 64 + dd];
#pragma unroll
      for (int j = 1; j < 24; ++j) vr += ldsW[row * PJ + j] * ldsTab[j * 64 + dd];
      outb[(size_t)(l0 + row) * ROWSTRIDE + dd] = (accO[dt][r] + vr) * inv[r];
    }
  }
}

extern "C" void kernel_launch(void* const* d_in, const int* in_sizes, int n_in,
                              void* d_out, int out_size, void* d_ws, size_t ws_size,
                              hipStream_t stream) {
  const float* x = (const float*)d_in[0];
  const float* y = (const float*)d_in[1];
  const float* vx = (const float*)d_in[2];
  const float* vy = (const float*)d_in[3];
  const float* relk = (const float*)d_in[4];
  const float* relvx = (const float*)d_in[5];
  const float* relvy = (const float*)d_in[6];
  float* out = (float*)d_out;
  float* out2 = out + (size_t)BB * LQ * HH * EE;

  float* P = (float*)d_ws;  // [32][1024][PJ] f32 = 3.4 MB

  k_relproj<<<NP * LQ, 64, 0, stream>>>(x, relk, P);
  k_fused<0><<<dim3(16, NP), 256, 0, stream>>>(x, y, vy, relvy, P, out);
  k_fused<1><<<dim3(16, NP), 256, 0, stream>>>(y, x, vx, relvx, P, out2);
}